// Round 4
// baseline (57.053 us; speedup 1.0000x reference)
//
#include <hip/hip_runtime.h>

#define BSZ 256
#define DDIM 1024
#define MARGIN 0.2f
#define WPB 4   // waves per block
#define PPW 8   // pairs (i values) per wave

typedef float f32x4 __attribute__((ext_vector_type(4)));

// Kernel 1: scores[i*B+j] = dot(im[j], s[i,j,:])
// One wave per (j, i-octet): im[j] loaded into registers once, then 8 rows
// of s are streamed (non-temporally) against it. 8192 waves = 32/CU.
__global__ __launch_bounds__(256) void scores_kernel(const float* __restrict__ im,
                                                     const float* __restrict__ s,
                                                     float* __restrict__ scores) {
    const int wave = threadIdx.x >> 6;
    const int lane = threadIdx.x & 63;
    const int w = blockIdx.x * WPB + wave;        // wave id in [0, 8192)
    const int j = w & (BSZ - 1);
    const int iBase = (w >> 8) * PPW;

    const f32x4* ip = reinterpret_cast<const f32x4*>(im + (size_t)j * DDIM);
    f32x4 b0 = ip[0 * 64 + lane];
    f32x4 b1 = ip[1 * 64 + lane];
    f32x4 b2 = ip[2 * 64 + lane];
    f32x4 b3 = ip[3 * 64 + lane];

#pragma unroll
    for (int it = 0; it < PPW; ++it) {
        const int p = (iBase + it) * BSZ + j;
        const f32x4* sp = reinterpret_cast<const f32x4*>(s + (size_t)p * DDIM);
        f32x4 a0 = __builtin_nontemporal_load(&sp[0 * 64 + lane]);
        f32x4 a1 = __builtin_nontemporal_load(&sp[1 * 64 + lane]);
        f32x4 a2 = __builtin_nontemporal_load(&sp[2 * 64 + lane]);
        f32x4 a3 = __builtin_nontemporal_load(&sp[3 * 64 + lane]);
        float acc = a0.x * b0.x + a0.y * b0.y + a0.z * b0.z + a0.w * b0.w;
        acc += a1.x * b1.x + a1.y * b1.y + a1.z * b1.z + a1.w * b1.w;
        acc += a2.x * b2.x + a2.y * b2.y + a2.z * b2.z + a2.w * b2.w;
        acc += a3.x * b3.x + a3.y * b3.y + a3.z * b3.z + a3.w * b3.w;
#pragma unroll
        for (int off = 32; off > 0; off >>= 1) acc += __shfl_down(acc, off);
        if (lane == 0) scores[p] = acc;
    }
}

// Kernel 2 (fused epilogue): block t computes partial[t] = rowmax + colmax
// (relu-margin, diagonal masked); the last block to finish deterministically
// sums the 256 partials and writes the scalar.
__global__ __launch_bounds__(256) void epilogue_kernel(const float* __restrict__ scores,
                                                       float* __restrict__ partial,
                                                       unsigned* __restrict__ counter,
                                                       float* __restrict__ out) {
    const int t = blockIdx.x;
    const int j = threadIdx.x;
    const int wave = j >> 6;
    const int lane = j & 63;
    __shared__ float wr[4], wc[4];
    __shared__ bool isLast;

    const float dg = scores[t * BSZ + t];
    float rowv = 0.0f, colv = 0.0f;
    if (j != t) {
        rowv = fmaxf(MARGIN + scores[t * BSZ + j] - dg, 0.0f);
        colv = fmaxf(MARGIN + scores[j * BSZ + t] - dg, 0.0f);
    }
#pragma unroll
    for (int off = 32; off > 0; off >>= 1) {
        rowv = fmaxf(rowv, __shfl_down(rowv, off));
        colv = fmaxf(colv, __shfl_down(colv, off));
    }
    if (lane == 0) { wr[wave] = rowv; wc[wave] = colv; }
    __syncthreads();
    if (j == 0) {
        float rm = fmaxf(fmaxf(wr[0], wr[1]), fmaxf(wr[2], wr[3]));
        float cm = fmaxf(fmaxf(wc[0], wc[1]), fmaxf(wc[2], wc[3]));
        partial[t] = rm + cm;
        __threadfence();                      // release partial[t]
        unsigned c = atomicAdd(counter, 1u);  // device-scope
        isLast = (c == (unsigned)(gridDim.x - 1));
    }
    __syncthreads();

    if (isLast) {
        __threadfence();                      // acquire all partials
        __shared__ float wsum[4];
        float v = partial[j];
#pragma unroll
        for (int off = 32; off > 0; off >>= 1) v += __shfl_down(v, off);
        if (lane == 0) wsum[wave] = v;
        __syncthreads();
        if (j == 0) out[0] = wsum[0] + wsum[1] + wsum[2] + wsum[3];
    }
}

extern "C" void kernel_launch(void* const* d_in, const int* in_sizes, int n_in,
                              void* d_out, int out_size, void* d_ws, size_t ws_size,
                              hipStream_t stream) {
    const float* im = (const float*)d_in[0];   // [B, D]
    const float* s  = (const float*)d_in[1];   // [B, B, D]
    float* out = (float*)d_out;                // scalar
    float* scores  = (float*)d_ws;             // B*B floats
    float* partial = scores + BSZ * BSZ;       // B floats
    unsigned* counter = (unsigned*)(partial + BSZ);  // 1 u32, reset each call

    (void)hipMemsetAsync(counter, 0, sizeof(unsigned), stream);

    const int nWaves = (BSZ * BSZ) / PPW;      // 8192
    scores_kernel<<<nWaves / WPB, 256, 0, stream>>>(im, s, scores);
    epilogue_kernel<<<BSZ, 256, 0, stream>>>(scores, partial, counter, out);
}

// Round 5
// 56.582 us; speedup vs baseline: 1.0083x; 1.0083x over previous
//
#include <hip/hip_runtime.h>

#define BSZ 256
#define DDIM 1024
#define MARGIN 0.2f
#define WPB 4   // waves per block
#define PPW 8   // pairs (i values) per wave

typedef float f32x4 __attribute__((ext_vector_type(4)));

// Kernel 1: scores[i*B+j] = dot(im[j], s[i,j,:])
// One wave per (j, i-octet): im[j] loaded into registers once, then 8 rows
// of s are streamed against it. 8192 waves = 32/CU.
__global__ __launch_bounds__(256) void scores_kernel(const float* __restrict__ im,
                                                     const float* __restrict__ s,
                                                     float* __restrict__ scores) {
    const int wave = threadIdx.x >> 6;
    const int lane = threadIdx.x & 63;
    const int w = blockIdx.x * WPB + wave;        // wave id in [0, 8192)
    const int j = w & (BSZ - 1);
    const int iBase = (w >> 8) * PPW;

    const f32x4* ip = reinterpret_cast<const f32x4*>(im + (size_t)j * DDIM);
    f32x4 b0 = ip[0 * 64 + lane];
    f32x4 b1 = ip[1 * 64 + lane];
    f32x4 b2 = ip[2 * 64 + lane];
    f32x4 b3 = ip[3 * 64 + lane];

#pragma unroll
    for (int it = 0; it < PPW; ++it) {
        const int p = (iBase + it) * BSZ + j;
        const f32x4* sp = reinterpret_cast<const f32x4*>(s + (size_t)p * DDIM);
        f32x4 a0 = sp[0 * 64 + lane];
        f32x4 a1 = sp[1 * 64 + lane];
        f32x4 a2 = sp[2 * 64 + lane];
        f32x4 a3 = sp[3 * 64 + lane];
        float acc = a0.x * b0.x + a0.y * b0.y + a0.z * b0.z + a0.w * b0.w;
        acc += a1.x * b1.x + a1.y * b1.y + a1.z * b1.z + a1.w * b1.w;
        acc += a2.x * b2.x + a2.y * b2.y + a2.z * b2.z + a2.w * b2.w;
        acc += a3.x * b3.x + a3.y * b3.y + a3.z * b3.z + a3.w * b3.w;
#pragma unroll
        for (int off = 32; off > 0; off >>= 1) acc += __shfl_down(acc, off);
        if (lane == 0) scores[p] = acc;
    }
}

// Kernel 2 (fused epilogue): block t computes partial[t] = rowmax + colmax
// (relu-margin, diagonal masked); the last block to finish deterministically
// sums the 256 partials and writes the scalar.
__global__ __launch_bounds__(256) void epilogue_kernel(const float* __restrict__ scores,
                                                       float* __restrict__ partial,
                                                       unsigned* __restrict__ counter,
                                                       float* __restrict__ out) {
    const int t = blockIdx.x;
    const int j = threadIdx.x;
    const int wave = j >> 6;
    const int lane = j & 63;
    __shared__ float wr[4], wc[4];
    __shared__ bool isLast;

    const float dg = scores[t * BSZ + t];
    float rowv = 0.0f, colv = 0.0f;
    if (j != t) {
        rowv = fmaxf(MARGIN + scores[t * BSZ + j] - dg, 0.0f);
        colv = fmaxf(MARGIN + scores[j * BSZ + t] - dg, 0.0f);
    }
#pragma unroll
    for (int off = 32; off > 0; off >>= 1) {
        rowv = fmaxf(rowv, __shfl_down(rowv, off));
        colv = fmaxf(colv, __shfl_down(colv, off));
    }
    if (lane == 0) { wr[wave] = rowv; wc[wave] = colv; }
    __syncthreads();
    if (j == 0) {
        float rm = fmaxf(fmaxf(wr[0], wr[1]), fmaxf(wr[2], wr[3]));
        float cm = fmaxf(fmaxf(wc[0], wc[1]), fmaxf(wc[2], wc[3]));
        partial[t] = rm + cm;
        __threadfence();                      // release partial[t]
        unsigned c = atomicAdd(counter, 1u);  // device-scope
        isLast = (c == (unsigned)(gridDim.x - 1));
    }
    __syncthreads();

    if (isLast) {
        __threadfence();                      // acquire all partials
        __shared__ float wsum[4];
        float v = partial[j];
#pragma unroll
        for (int off = 32; off > 0; off >>= 1) v += __shfl_down(v, off);
        if (lane == 0) wsum[wave] = v;
        __syncthreads();
        if (j == 0) out[0] = wsum[0] + wsum[1] + wsum[2] + wsum[3];
    }
}

extern "C" void kernel_launch(void* const* d_in, const int* in_sizes, int n_in,
                              void* d_out, int out_size, void* d_ws, size_t ws_size,
                              hipStream_t stream) {
    const float* im = (const float*)d_in[0];   // [B, D]
    const float* s  = (const float*)d_in[1];   // [B, B, D]
    float* out = (float*)d_out;                // scalar
    float* scores  = (float*)d_ws;             // B*B floats
    float* partial = scores + BSZ * BSZ;       // B floats
    unsigned* counter = (unsigned*)(partial + BSZ);  // 1 u32, reset each call

    (void)hipMemsetAsync(counter, 0, sizeof(unsigned), stream);

    const int nWaves = (BSZ * BSZ) / PPW;      // 8192
    scores_kernel<<<nWaves / WPB, 256, 0, stream>>>(im, s, scores);
    epilogue_kernel<<<BSZ, 256, 0, stream>>>(scores, partial, counter, out);
}

// Round 6
// 46.931 us; speedup vs baseline: 1.2157x; 1.2056x over previous
//
#include <hip/hip_runtime.h>

#define BSZ 256
#define DDIM 1024
#define MARGIN 0.2f
#define WPB 4   // waves per block
#define PPW 8   // pairs (i values) per wave

typedef float f32x4 __attribute__((ext_vector_type(4)));

// Kernel 1: scores[i*B+j] = dot(im[j], s[i,j,:])
// One wave per (j, i-octet): im[j] loaded into registers once, then 8 rows
// of s are streamed against it. 8192 waves = 32/CU.
__global__ __launch_bounds__(256) void scores_kernel(const float* __restrict__ im,
                                                     const float* __restrict__ s,
                                                     float* __restrict__ scores) {
    const int wave = threadIdx.x >> 6;
    const int lane = threadIdx.x & 63;
    const int w = blockIdx.x * WPB + wave;        // wave id in [0, 8192)
    const int j = w & (BSZ - 1);
    const int iBase = (w >> 8) * PPW;

    const f32x4* ip = reinterpret_cast<const f32x4*>(im + (size_t)j * DDIM);
    f32x4 b0 = ip[0 * 64 + lane];
    f32x4 b1 = ip[1 * 64 + lane];
    f32x4 b2 = ip[2 * 64 + lane];
    f32x4 b3 = ip[3 * 64 + lane];

#pragma unroll
    for (int it = 0; it < PPW; ++it) {
        const int p = (iBase + it) * BSZ + j;
        const f32x4* sp = reinterpret_cast<const f32x4*>(s + (size_t)p * DDIM);
        f32x4 a0 = sp[0 * 64 + lane];
        f32x4 a1 = sp[1 * 64 + lane];
        f32x4 a2 = sp[2 * 64 + lane];
        f32x4 a3 = sp[3 * 64 + lane];
        float acc = a0.x * b0.x + a0.y * b0.y + a0.z * b0.z + a0.w * b0.w;
        acc += a1.x * b1.x + a1.y * b1.y + a1.z * b1.z + a1.w * b1.w;
        acc += a2.x * b2.x + a2.y * b2.y + a2.z * b2.z + a2.w * b2.w;
        acc += a3.x * b3.x + a3.y * b3.y + a3.z * b3.z + a3.w * b3.w;
#pragma unroll
        for (int off = 32; off > 0; off >>= 1) acc += __shfl_down(acc, off);
        if (lane == 0) scores[p] = acc;
    }
}

// Kernel 2: block t computes rowmax(relu(margin + S[t,:] - dg)) and
// colmax(relu(margin + S[:,t] - dg)), dg = S[t,t]; writes partial[t].
__global__ __launch_bounds__(256) void rowcol_kernel(const float* __restrict__ scores,
                                                     float* __restrict__ partial) {
    const int t = blockIdx.x;
    const int j = threadIdx.x;
    __shared__ float wr[4], wc[4];

    const float dg = scores[t * BSZ + t];
    float rowv = 0.0f, colv = 0.0f;
    if (j != t) {
        rowv = fmaxf(MARGIN + scores[t * BSZ + j] - dg, 0.0f);
        colv = fmaxf(MARGIN + scores[j * BSZ + t] - dg, 0.0f);
    }
#pragma unroll
    for (int off = 32; off > 0; off >>= 1) {
        rowv = fmaxf(rowv, __shfl_down(rowv, off));
        colv = fmaxf(colv, __shfl_down(colv, off));
    }
    const int wave = j >> 6;
    const int lane = j & 63;
    if (lane == 0) { wr[wave] = rowv; wc[wave] = colv; }
    __syncthreads();
    if (j == 0) {
        float rm = fmaxf(fmaxf(wr[0], wr[1]), fmaxf(wr[2], wr[3]));
        float cm = fmaxf(fmaxf(wc[0], wc[1]), fmaxf(wc[2], wc[3]));
        partial[t] = rm + cm;
    }
}

// Kernel 3: sum 256 partials -> scalar out (deterministic).
__global__ __launch_bounds__(256) void sum_kernel(const float* __restrict__ partial,
                                                  float* __restrict__ out) {
    const int t = threadIdx.x;
    __shared__ float wsum[4];
    float v = partial[t];
#pragma unroll
    for (int off = 32; off > 0; off >>= 1) v += __shfl_down(v, off);
    if ((t & 63) == 0) wsum[t >> 6] = v;
    __syncthreads();
    if (t == 0) out[0] = wsum[0] + wsum[1] + wsum[2] + wsum[3];
}

extern "C" void kernel_launch(void* const* d_in, const int* in_sizes, int n_in,
                              void* d_out, int out_size, void* d_ws, size_t ws_size,
                              hipStream_t stream) {
    const float* im = (const float*)d_in[0];   // [B, D]
    const float* s  = (const float*)d_in[1];   // [B, B, D]
    float* out = (float*)d_out;                // scalar
    float* scores  = (float*)d_ws;             // B*B floats
    float* partial = scores + BSZ * BSZ;       // B floats

    const int nWaves = (BSZ * BSZ) / PPW;      // 8192
    scores_kernel<<<nWaves / WPB, 256, 0, stream>>>(im, s, scores);
    rowcol_kernel<<<BSZ, 256, 0, stream>>>(scores, partial);
    sum_kernel<<<1, 256, 0, stream>>>(partial, out);
}